// Round 8
// baseline (1060.718 us; speedup 1.0000x reference)
//
#include <hip/hip_runtime.h>
#include <math.h>

#define TSTEPS 200
#define NROTS  40      // 5*NQ*NL params per timestep circuit (2 layers)
#define BPB    5       // batch elements per block
#define BLK    1024    // 16 waves; lanes 0..999 carry real circuits (97.7% useful)
#define NGRP   (BLK / 8)   // 128 aligned 8-lane groups (200 % 8 == 0: no b-straddle)
#define GPB    (TSTEPS / 8) // 25 groups per batch element
#define DEG    3

__device__ __forceinline__ void fsc(float h, float& s, float& c) {
    s = __sinf(h); c = __cosf(h);
}

// Fused U = RZ(h3)*RY(h2)*RX(h1); only u00,u01 needed. Verified rounds 2-7.
__device__ __forceinline__ void make_u(float h1, float h2, float h3, float* u) {
    float s1, c1, s2, c2, s3, c3;
    fsc(h1, s1, c1); fsc(h2, s2, c2); fsc(h3, s3, c3);
    float A = c1 * c2, Bv = s1 * s2, C = c1 * s2, D = s1 * c2;
    u[0] =  c3 * A + s3 * Bv;      // u00r
    u[1] =  c3 * Bv - s3 * A;      // u00i
    u[2] = -(c3 * C + s3 * D);     // u01r
    u[3] =  s3 * C - c3 * D;       // u01i
}

// Planar state: V[0..15] = real amps, V[16..31] = imag. Wire w <-> bit (8>>w).
// Scalar-planar form is the verified-fast codegen shape (rounds 5/6: VGPR 60,
// VALUBusy 98%). ext_vector forms regressed twice (rounds 4, 7) - do not pack.
template<int BIT>
__device__ __forceinline__ void g_u2(float* V, const float* u) {
    const float u00r = u[0], u00i = u[1], u01r = u[2], u01i = u[3];
    #pragma unroll
    for (int p = 0; p < 16; ++p) {
        if (p & BIT) continue;
        const int q = p | BIT;
        float a0r = V[p], a0i = V[16 + p], a1r = V[q], a1i = V[16 + q];
        V[p]      =  u00r * a0r - u00i * a0i + u01r * a1r - u01i * a1i;
        V[16 + p] =  u00r * a0i + u00i * a0r + u01r * a1i + u01i * a1r;
        V[q]      = -u01r * a0r - u01i * a0i + u00r * a1r + u00i * a1i;
        V[16 + q] = -u01r * a0i + u01i * a0r + u00r * a1i - u00i * a1r;
    }
}

template<int CBIT, int TBIT>
__device__ __forceinline__ void g_crx_pre(float* V, float s, float c) {
    #pragma unroll
    for (int p = 0; p < 16; ++p) {
        if (!(p & CBIT) || (p & TBIT)) continue;   // control=1, target=0 rows
        const int q = p | TBIT;
        float a0r = V[p], a0i = V[16 + p], a1r = V[q], a1i = V[16 + q];
        V[p]      = c * a0r + s * a1i;
        V[16 + p] = c * a0i - s * a1r;
        V[q]      = c * a1r + s * a0i;
        V[16 + q] = c * a1i - s * a0r;
    }
}

__device__ __forceinline__ void apply_layer_pre(float* V, const float (&u)[4][4],
                                                const float (&cs)[8][2]) {
    g_u2<8>(V, u[0]); g_u2<4>(V, u[1]); g_u2<2>(V, u[2]); g_u2<1>(V, u[3]);
    g_crx_pre<8, 4>(V, cs[0][0], cs[0][1]);
    g_crx_pre<4, 2>(V, cs[1][0], cs[1][1]);
    g_crx_pre<2, 1>(V, cs[2][0], cs[2][1]);
    g_crx_pre<1, 8>(V, cs[3][0], cs[3][1]);
    g_crx_pre<1, 2>(V, cs[4][0], cs[4][1]);
    g_crx_pre<2, 4>(V, cs[5][0], cs[5][1]);
    g_crx_pre<4, 8>(V, cs[6][0], cs[6][1]);
    g_crx_pre<8, 1>(V, cs[7][0], cs[7][1]);
}

// Reduce-scatter halving step; template-constant indices (round-3-verified).
template<int S, int HALF>
__device__ __forceinline__ void rstep(float* V, int lane) {
    const bool hi = (lane >> S) & 1;
    #pragma unroll
    for (int j = 0; j < HALF; ++j) {
        float send = hi ? V[j] : V[j + HALF];
        float keep = hi ? V[j + HALF] : V[j];
        V[j] = keep + __shfl_xor(send, 1 << S, 64);
    }
}

// 5 batch elements per 1024-thread block; thread -> (b_local = tid/200, t = tid%200).
extern "C" __global__ void __launch_bounds__(BLK)
qac_kernel(const float* __restrict__ tp,    // (B, T, NROTS)
           const float* __restrict__ poly,  // (DEG+1,)
           const float* __restrict__ mixr,  // (T,)
           const float* __restrict__ mixi,  // (T,)
           const float* __restrict__ qff,   // (20,)
           float* __restrict__ out,         // (B, 12)
           int B)
{
    __shared__ float s_part[NGRP][32];   // 16 KB group partials
    __shared__ float s_w[BPB][32];       // work vectors   (0..15 re, 16..31 im)
    __shared__ float s_acc[BPB][32];     // QSVT accumulators

    const int tid = threadIdx.x;
    const int bl  = tid / TSTEPS;                    // 0..5 (5 = filler lanes)
    const int t   = tid - bl * TSTEPS;
    const int bli = (bl < BPB) ? bl : (BPB - 1);     // clamped local batch
    const int bg  = blockIdx.x * BPB + bli;          // global batch
    const bool act = (bl < BPB) && (bg < B);
    const int beff = (bg < B) ? bg : (B - 1);        // clamp for safe loads

    if (tid < BPB * 32) {
        const int v = tid & 31;
        s_w[tid >> 5][v]   = (v == 0) ? 1.f : 0.f;
        s_acc[tid >> 5][v] = (v == 0) ? poly[0] : 0.f;
    }

    const float cr_ = act ? mixr[t] : 0.f;
    const float ci_ = act ? mixi[t] : 0.f;
    const float4* p4 = (const float4*)(tp + ((size_t)beff * TSTEPS + t) * NROTS);

    // ---- hoist ALL trig out of the QSVT loop (params identical each pass) ----
    float tu[2][4][4];   // [layer][wire][u00r,u00i,u01r,u01i]
    float tc[2][8][2];   // [layer][crx gate][s,c]
    #pragma unroll
    for (int L = 0; L < 2; ++L) {
        float4 f0 = p4[5*L+0], f1 = p4[5*L+1], f2v = p4[5*L+2], f3 = p4[5*L+3], f4 = p4[5*L+4];
        make_u(0.5f*f0.x,  0.5f*f0.y,  0.5f*f0.z,  tu[L][0]);
        make_u(0.5f*f0.w,  0.5f*f1.x,  0.5f*f1.y,  tu[L][1]);
        make_u(0.5f*f1.z,  0.5f*f1.w,  0.5f*f2v.x, tu[L][2]);
        make_u(0.5f*f2v.y, 0.5f*f2v.z, 0.5f*f2v.w, tu[L][3]);
        fsc(0.5f*f3.x, tc[L][0][0], tc[L][0][1]);
        fsc(0.5f*f3.y, tc[L][1][0], tc[L][1][1]);
        fsc(0.5f*f3.z, tc[L][2][0], tc[L][2][1]);
        fsc(0.5f*f3.w, tc[L][3][0], tc[L][3][1]);
        fsc(0.5f*f4.x, tc[L][4][0], tc[L][4][1]);
        fsc(0.5f*f4.y, tc[L][5][0], tc[L][5][1]);
        fsc(0.5f*f4.z, tc[L][6][0], tc[L][6][1]);
        fsc(0.5f*f4.w, tc[L][7][0], tc[L][7][1]);
    }

    // 3-step reduce-scatter leaves lane with V[j] = group-sum of value
    // v = j + 4*l2 + 8*l1 + 16*l0  (j in 0..3); groups are tid/8.
    const int g     = tid >> 3;
    const int vbase = 16 * (tid & 1) + 8 * ((tid >> 1) & 1) + 4 * ((tid >> 2) & 1);

    __syncthreads();

    #pragma unroll 1
    for (int k = 1; k <= DEG; ++k) {
        float V[32];
        #pragma unroll
        for (int i = 0; i < 32; ++i) V[i] = s_w[bli][i];

        apply_layer_pre(V, tu[0], tc[0]);
        apply_layer_pre(V, tu[1], tc[1]);

        // scale by this timestep's LCU coefficient (0 for filler / OOB lanes)
        #pragma unroll
        for (int i = 0; i < 16; ++i) {
            float r = V[i], im = V[16 + i];
            V[i]      = r * cr_ - im * ci_;
            V[16 + i] = r * ci_ + im * cr_;
        }

        // segmented reduce: 3 halving steps over lane bits 0..2 (8-lane groups,
        // always within one batch element since 200 % 8 == 0)
        rstep<0, 16>(V, tid);
        rstep<1, 8>(V, tid);
        rstep<2, 4>(V, tid);
        float4 w4 = make_float4(V[0], V[1], V[2], V[3]);
        *(float4*)&s_part[g][vbase] = w4;

        __syncthreads();
        // stage 2: sum the 25 group-partials of each batch element
        if (tid < BPB * 32) {
            const int bb = tid >> 5, v = tid & 31;
            float r = 0.f;
            #pragma unroll
            for (int gi = 0; gi < GPB; ++gi) r += s_part[bb * GPB + gi][v];
            s_w[bb][v] = r;
            s_acc[bb][v] += poly[k] * r;
        }
        __syncthreads();
    }

    // ---- finalize: 16 lanes per batch element (verified round 2); shfl masks
    // < 16 stay within the aligned 16-lane group of each bb ----
    if (tid < BPB * 16) {
        const int bb = tid >> 4;
        const int l  = tid & 15;
        const int bglob = blockIdx.x * BPB + bb;
        if (bglob < B) {
            const float* accf = s_acc[bb];
            float l1 = fabsf(poly[0]) + fabsf(poly[1]) + fabsf(poly[2]) + fabsf(poly[3]);
            float inv = 1.f / l1;
            float ar = accf[l] * inv, ai = accf[16 + l] * inv;
            float n2 = ar * ar + ai * ai;
            #pragma unroll
            for (int o = 1; o < 16; o <<= 1) n2 += __shfl_xor(n2, o, 64);
            float sc = 1.f / (sqrtf(n2) + 1e-9f);
            ar *= sc; ai *= sc;

            float s, c, pr, pi, se, ce, t0;
            #pragma unroll
            for (int w = 0; w < 4; ++w) {
                const int BIT = 8 >> w;
                fsc(0.5f * qff[3 * w + 0], s, c);            // RX
                pr = __shfl_xor(ar, BIT, 64); pi = __shfl_xor(ai, BIT, 64);
                t0 = c * ar + s * pi; ai = c * ai - s * pr; ar = t0;
                fsc(0.5f * qff[3 * w + 1], s, c);            // RY
                pr = __shfl_xor(ar, BIT, 64); pi = __shfl_xor(ai, BIT, 64);
                se = (l & BIT) ? s : -s;
                t0 = c * ar + se * pr; ai = c * ai + se * pi; ar = t0;
                fsc(0.5f * qff[3 * w + 2], s, c);            // RZ
                se = (l & BIT) ? s : -s;
                t0 = c * ar - se * ai; ai = c * ai + se * ar; ar = t0;
            }
            #define CRXF(CB, TB, hp) { fsc(0.5f * (hp), s, c);                        \
                pr = __shfl_xor(ar, TB, 64); pi = __shfl_xor(ai, TB, 64);             \
                ce = (l & CB) ? c : 1.f; se = (l & CB) ? s : 0.f;                     \
                t0 = ce * ar + se * pi; ai = ce * ai - se * pr; ar = t0; }
            CRXF(8, 4, qff[12]) CRXF(4, 2, qff[13]) CRXF(2, 1, qff[14]) CRXF(1, 8, qff[15])
            CRXF(1, 2, qff[16]) CRXF(2, 4, qff[17]) CRXF(4, 8, qff[18]) CRXF(8, 1, qff[19])
            #undef CRXF

            float* o = out + (size_t)bglob * 12;
            #pragma unroll
            for (int w = 0; w < 4; ++w) {
                const int BIT = 8 >> w;
                pr = __shfl_xor(ar, BIT, 64); pi = __shfl_xor(ai, BIT, 64);
                float m = (l & BIT) ? 0.f : 1.f;
                float X = m * 2.f * (ar * pr + ai * pi);
                float Y = m * 2.f * (ar * pi - ai * pr);
                float Z = m * (ar * ar + ai * ai - pr * pr - pi * pi);
                #pragma unroll
                for (int of = 1; of < 16; of <<= 1) {
                    X += __shfl_xor(X, of, 64);
                    Y += __shfl_xor(Y, of, 64);
                    Z += __shfl_xor(Z, of, 64);
                }
                if (l == 0) { o[w] = X; o[4 + w] = Y; o[8 + w] = Z; }
            }
        }
    }
}

extern "C" void kernel_launch(void* const* d_in, const int* in_sizes, int n_in,
                              void* d_out, int out_size, void* d_ws, size_t ws_size,
                              hipStream_t stream) {
    const float* tp   = (const float*)d_in[0];
    const float* poly = (const float*)d_in[1];
    const float* mixr = (const float*)d_in[2];
    const float* mixi = (const float*)d_in[3];
    const float* qff  = (const float*)d_in[4];
    float* out = (float*)d_out;
    const int B = in_sizes[0] / (TSTEPS * NROTS);   // 2048
    const int nblk = (B + BPB - 1) / BPB;           // 410
    qac_kernel<<<dim3(nblk), dim3(BLK), 0, stream>>>(tp, poly, mixr, mixi, qff, out, B);
}

// Round 9
// 154.580 us; speedup vs baseline: 6.8619x; 6.8619x over previous
//
#include <hip/hip_runtime.h>
#include <math.h>

#define TSTEPS 200
#define NROTS  40      // 5*NQ*NL params per timestep circuit (2 layers)
#define BLK    256
#define DEG    3

__device__ __forceinline__ void fsc(float h, float& s, float& c) {
    s = __sinf(h); c = __cosf(h);
}

// Fused U = RZ(h3)*RY(h2)*RX(h1); only u00,u01 needed (u11=conj(u00), u10=-conj(u01)).
// Verified rounds 2-8.
__device__ __forceinline__ void make_u(float h1, float h2, float h3, float* u) {
    float s1, c1, s2, c2, s3, c3;
    fsc(h1, s1, c1); fsc(h2, s2, c2); fsc(h3, s3, c3);
    float A = c1 * c2, Bv = s1 * s2, C = c1 * s2, D = s1 * c2;
    u[0] =  c3 * A + s3 * Bv;      // u00r
    u[1] =  c3 * Bv - s3 * A;      // u00i
    u[2] = -(c3 * C + s3 * D);     // u01r
    u[3] =  s3 * C - c3 * D;       // u01i
}

// Planar state: V[0..15] = real amps, V[16..31] = imag. Wire w <-> bit (8>>w).
// Scalar-planar form is the verified-fast codegen shape (rounds 5/6: VALUBusy 98%).
// ext_vector forms regressed twice (rounds 4, 7); block-shape changes regressed
// (round 8). Do not restructure.
template<int BIT>
__device__ __forceinline__ void g_u2(float* V, const float* u) {
    const float u00r = u[0], u00i = u[1], u01r = u[2], u01i = u[3];
    #pragma unroll
    for (int p = 0; p < 16; ++p) {
        if (p & BIT) continue;
        const int q = p | BIT;
        float a0r = V[p], a0i = V[16 + p], a1r = V[q], a1i = V[16 + q];
        V[p]      =  u00r * a0r - u00i * a0i + u01r * a1r - u01i * a1i;
        V[16 + p] =  u00r * a0i + u00i * a0r + u01r * a1i + u01i * a1r;
        V[q]      = -u01r * a0r - u01i * a0i + u00r * a1r + u00i * a1i;
        V[16 + q] = -u01r * a0i + u01i * a0r + u00r * a1i - u00i * a1r;
    }
}

// Sparse g_u2 for pass-1 tensor-product build: before the gate on BIT, the
// nonzero amps are exactly the multiples of 2*BIT (partner a1 = 0). Derived
// from the verified g_u2 formula with a1r=a1i=0.
template<int BIT>
__device__ __forceinline__ void g_u2_sparse(float* V, const float* u) {
    const float u00r = u[0], u00i = u[1], u01r = u[2], u01i = u[3];
    #pragma unroll
    for (int p = 0; p < 16; p += 2 * BIT) {
        const int q = p | BIT;
        float ar = V[p], ai = V[16 + p];
        V[p]      =  u00r * ar - u00i * ai;
        V[16 + p] =  u00r * ai + u00i * ar;
        V[q]      = -u01r * ar - u01i * ai;
        V[16 + q] = -u01r * ai + u01i * ar;
    }
}

template<int CBIT, int TBIT>
__device__ __forceinline__ void g_crx_pre(float* V, float s, float c) {
    #pragma unroll
    for (int p = 0; p < 16; ++p) {
        if (!(p & CBIT) || (p & TBIT)) continue;   // control=1, target=0 rows
        const int q = p | TBIT;
        float a0r = V[p], a0i = V[16 + p], a1r = V[q], a1i = V[16 + q];
        V[p]      = c * a0r + s * a1i;
        V[16 + p] = c * a0i - s * a1r;
        V[q]      = c * a1r + s * a0i;
        V[16 + q] = c * a1i - s * a0r;
    }
}

__device__ __forceinline__ void apply_crx_ring(float* V, const float (&cs)[8][2]) {
    g_crx_pre<8, 4>(V, cs[0][0], cs[0][1]);
    g_crx_pre<4, 2>(V, cs[1][0], cs[1][1]);
    g_crx_pre<2, 1>(V, cs[2][0], cs[2][1]);
    g_crx_pre<1, 8>(V, cs[3][0], cs[3][1]);
    g_crx_pre<1, 2>(V, cs[4][0], cs[4][1]);
    g_crx_pre<2, 4>(V, cs[5][0], cs[5][1]);
    g_crx_pre<4, 8>(V, cs[6][0], cs[6][1]);
    g_crx_pre<8, 1>(V, cs[7][0], cs[7][1]);
}

__device__ __forceinline__ void apply_layer_pre(float* V, const float (&u)[4][4],
                                                const float (&cs)[8][2]) {
    g_u2<8>(V, u[0]); g_u2<4>(V, u[1]); g_u2<2>(V, u[2]); g_u2<1>(V, u[3]);
    apply_crx_ring(V, cs);
}

// Reduce-scatter halving step; template-constant indices (round-3-verified).
template<int S, int HALF>
__device__ __forceinline__ void rstep(float* V, int lane) {
    const bool hi = (lane >> S) & 1;
    #pragma unroll
    for (int j = 0; j < HALF; ++j) {
        float send = hi ? V[j] : V[j + HALF];
        float keep = hi ? V[j + HALF] : V[j];
        V[j] = keep + __shfl_xor(send, 1 << S, 64);
    }
}

// One block per batch element. Thread t simulates timestep t (t>=200: coeff 0).
extern "C" __global__ void __launch_bounds__(BLK)
qac_kernel(const float* __restrict__ tp,    // (B, T, NROTS)
           const float* __restrict__ poly,  // (DEG+1,)
           const float* __restrict__ mixr,  // (T,)
           const float* __restrict__ mixi,  // (T,)
           const float* __restrict__ qff,   // (20,)
           float* __restrict__ out)         // (B, 12)
{
    __shared__ float s_red[4][32];   // per-wave reduced values (value-indexed)
    __shared__ float s_w[32];        // work vector  (0..15 re, 16..31 im)
    __shared__ float s_acc[32];      // QSVT accumulator, same layout

    const int b    = blockIdx.x;
    const int tid  = threadIdx.x;
    const int lane = tid & 63;
    const int wv   = tid >> 6;

    // s_acc is initialized and updated by the SAME threads (tid<32) in stage 2,
    // so no barrier is needed before the peeled pass 1 (it doesn't read s_w).
    if (tid < 32) s_acc[tid] = (tid == 0) ? poly[0] : 0.f;

    float cr_ = 0.f, ci_ = 0.f;
    if (tid < TSTEPS) { cr_ = mixr[tid]; ci_ = mixi[tid]; }
    const int mt = (tid < TSTEPS) ? tid : (TSTEPS - 1);
    const float4* p4 = (const float4*)(tp + (size_t)b * (TSTEPS * NROTS) + mt * NROTS);

    // ---- hoist ALL trig out of the QSVT passes (params identical each pass) ----
    float tu[2][4][4];   // [layer][wire][u00r,u00i,u01r,u01i]
    float tc[2][8][2];   // [layer][crx gate][s,c]
    #pragma unroll
    for (int L = 0; L < 2; ++L) {
        float4 f0 = p4[5*L+0], f1 = p4[5*L+1], f2v = p4[5*L+2], f3 = p4[5*L+3], f4 = p4[5*L+4];
        make_u(0.5f*f0.x,  0.5f*f0.y,  0.5f*f0.z,  tu[L][0]);
        make_u(0.5f*f0.w,  0.5f*f1.x,  0.5f*f1.y,  tu[L][1]);
        make_u(0.5f*f1.z,  0.5f*f1.w,  0.5f*f2v.x, tu[L][2]);
        make_u(0.5f*f2v.y, 0.5f*f2v.z, 0.5f*f2v.w, tu[L][3]);
        fsc(0.5f*f3.x, tc[L][0][0], tc[L][0][1]);
        fsc(0.5f*f3.y, tc[L][1][0], tc[L][1][1]);
        fsc(0.5f*f3.z, tc[L][2][0], tc[L][2][1]);
        fsc(0.5f*f3.w, tc[L][3][0], tc[L][3][1]);
        fsc(0.5f*f4.x, tc[L][4][0], tc[L][4][1]);
        fsc(0.5f*f4.y, tc[L][5][0], tc[L][5][1]);
        fsc(0.5f*f4.z, tc[L][6][0], tc[L][6][1]);
        fsc(0.5f*f4.w, tc[L][7][0], tc[L][7][1]);
    }

    // reduce-scatter destination: value index bitrev5(lane&31) (verified round 2)
    const int vidx = ((lane & 1) << 4) | ((lane & 2) << 2) | (lane & 4) |
                     ((lane & 8) >> 2) | ((lane & 16) >> 4);

    // ================= pass k=1, peeled: input state is e0 =================
    {
        float V[32];
        // tensor-product build of layer-0's single-qubit gates applied to e0:
        // wire 0 (BIT 8) on (1,0) directly, then sparse gates (support 2->4->8->16)
        V[0]  =  tu[0][0][0]; V[16] = tu[0][0][1];
        V[8]  = -tu[0][0][2]; V[24] = tu[0][0][3];
        g_u2_sparse<4>(V, tu[0][1]);
        g_u2_sparse<2>(V, tu[0][2]);
        g_u2_sparse<1>(V, tu[0][3]);
        apply_crx_ring(V, tc[0]);
        apply_layer_pre(V, tu[1], tc[1]);

        #pragma unroll
        for (int i = 0; i < 16; ++i) {
            float r = V[i], im = V[16 + i];
            V[i]      = r * cr_ - im * ci_;
            V[16 + i] = r * ci_ + im * cr_;
        }

        rstep<0, 16>(V, lane);
        rstep<1, 8>(V, lane);
        rstep<2, 4>(V, lane);
        rstep<3, 2>(V, lane);
        rstep<4, 1>(V, lane);
        float tot = V[0] + __shfl_xor(V[0], 32, 64);
        if (lane < 32) s_red[wv][vidx] = tot;

        __syncthreads();
        if (tid < 32) {
            float r = s_red[0][tid] + s_red[1][tid] + s_red[2][tid] + s_red[3][tid];
            s_w[tid] = r;
            s_acc[tid] += poly[1] * r;
        }
        __syncthreads();
    }

    // ================= passes k=2,3: full gate stream on s_w =================
    #pragma unroll 1
    for (int k = 2; k <= DEG; ++k) {
        float V[32];
        #pragma unroll
        for (int i = 0; i < 32; ++i) V[i] = s_w[i];

        apply_layer_pre(V, tu[0], tc[0]);
        apply_layer_pre(V, tu[1], tc[1]);

        #pragma unroll
        for (int i = 0; i < 16; ++i) {
            float r = V[i], im = V[16 + i];
            V[i]      = r * cr_ - im * ci_;
            V[16 + i] = r * ci_ + im * cr_;
        }

        rstep<0, 16>(V, lane);
        rstep<1, 8>(V, lane);
        rstep<2, 4>(V, lane);
        rstep<3, 2>(V, lane);
        rstep<4, 1>(V, lane);
        float tot = V[0] + __shfl_xor(V[0], 32, 64);
        if (lane < 32) s_red[wv][vidx] = tot;

        __syncthreads();
        if (tid < 32) {
            float r = s_red[0][tid] + s_red[1][tid] + s_red[2][tid] + s_red[3][tid];
            s_w[tid] = r;
            s_acc[tid] += poly[k] * r;
        }
        __syncthreads();
    }

    // ---- finalize on wave 0, lane-per-amplitude (verified round 2) ----
    if (tid < 16) {
        const int l = tid;
        float l1 = fabsf(poly[0]) + fabsf(poly[1]) + fabsf(poly[2]) + fabsf(poly[3]);
        float inv = 1.f / l1;
        float ar = s_acc[l] * inv, ai = s_acc[16 + l] * inv;
        float n2 = ar * ar + ai * ai;
        #pragma unroll
        for (int o = 1; o < 16; o <<= 1) n2 += __shfl_xor(n2, o, 64);
        float sc = 1.f / (sqrtf(n2) + 1e-9f);
        ar *= sc; ai *= sc;

        float s, c, pr, pi, se, ce, t0;
        #pragma unroll
        for (int w = 0; w < 4; ++w) {
            const int BIT = 8 >> w;
            fsc(0.5f * qff[3 * w + 0], s, c);            // RX
            pr = __shfl_xor(ar, BIT, 64); pi = __shfl_xor(ai, BIT, 64);
            t0 = c * ar + s * pi; ai = c * ai - s * pr; ar = t0;
            fsc(0.5f * qff[3 * w + 1], s, c);            // RY
            pr = __shfl_xor(ar, BIT, 64); pi = __shfl_xor(ai, BIT, 64);
            se = (l & BIT) ? s : -s;
            t0 = c * ar + se * pr; ai = c * ai + se * pi; ar = t0;
            fsc(0.5f * qff[3 * w + 2], s, c);            // RZ
            se = (l & BIT) ? s : -s;
            t0 = c * ar - se * ai; ai = c * ai + se * ar; ar = t0;
        }
        #define CRXF(CB, TB, hp) { fsc(0.5f * (hp), s, c);                        \
            pr = __shfl_xor(ar, TB, 64); pi = __shfl_xor(ai, TB, 64);             \
            ce = (l & CB) ? c : 1.f; se = (l & CB) ? s : 0.f;                     \
            t0 = ce * ar + se * pi; ai = ce * ai - se * pr; ar = t0; }
        CRXF(8, 4, qff[12]) CRXF(4, 2, qff[13]) CRXF(2, 1, qff[14]) CRXF(1, 8, qff[15])
        CRXF(1, 2, qff[16]) CRXF(2, 4, qff[17]) CRXF(4, 8, qff[18]) CRXF(8, 1, qff[19])
        #undef CRXF

        float* o = out + (size_t)b * 12;
        #pragma unroll
        for (int w = 0; w < 4; ++w) {
            const int BIT = 8 >> w;
            pr = __shfl_xor(ar, BIT, 64); pi = __shfl_xor(ai, BIT, 64);
            float m = (l & BIT) ? 0.f : 1.f;
            float X = m * 2.f * (ar * pr + ai * pi);
            float Y = m * 2.f * (ar * pi - ai * pr);
            float Z = m * (ar * ar + ai * ai - pr * pr - pi * pi);
            #pragma unroll
            for (int of = 1; of < 16; of <<= 1) {
                X += __shfl_xor(X, of, 64);
                Y += __shfl_xor(Y, of, 64);
                Z += __shfl_xor(Z, of, 64);
            }
            if (l == 0) { o[w] = X; o[4 + w] = Y; o[8 + w] = Z; }
        }
    }
}

extern "C" void kernel_launch(void* const* d_in, const int* in_sizes, int n_in,
                              void* d_out, int out_size, void* d_ws, size_t ws_size,
                              hipStream_t stream) {
    const float* tp   = (const float*)d_in[0];
    const float* poly = (const float*)d_in[1];
    const float* mixr = (const float*)d_in[2];
    const float* mixi = (const float*)d_in[3];
    const float* qff  = (const float*)d_in[4];
    float* out = (float*)d_out;
    const int B = in_sizes[0] / (TSTEPS * NROTS);   // 2048
    qac_kernel<<<dim3(B), dim3(BLK), 0, stream>>>(tp, poly, mixr, mixi, qff, out);
}

// Round 10
// 147.408 us; speedup vs baseline: 7.1958x; 1.0487x over previous
//
#include <hip/hip_runtime.h>
#include <math.h>

#define TSTEPS 200
#define NROTS  40      // 5*NQ*NL params per timestep circuit (2 layers)
#define BLK    256
#define DEG    3

__device__ __forceinline__ void fsc(float h, float& s, float& c) {
    s = __sinf(h); c = __cosf(h);
}

// Fused U = RZ(h3)*RY(h2)*RX(h1); only u00,u01 needed (u11=conj(u00), u10=-conj(u01)).
// Verified rounds 2-9.
__device__ __forceinline__ void make_u(float h1, float h2, float h3, float* u) {
    float s1, c1, s2, c2, s3, c3;
    fsc(h1, s1, c1); fsc(h2, s2, c2); fsc(h3, s3, c3);
    float A = c1 * c2, Bv = s1 * s2, C = c1 * s2, D = s1 * c2;
    u[0] =  c3 * A + s3 * Bv;      // u00r
    u[1] =  c3 * Bv - s3 * A;      // u00i
    u[2] = -(c3 * C + s3 * D);     // u01r
    u[3] =  s3 * C - c3 * D;       // u01i
}

// Planar state: V[0..15] = real amps, V[16..31] = imag. Wire w <-> bit (8>>w).
// THIS SHAPE IS A VERIFIED CODEGEN OPTIMUM (rounds 5/6: 76 us, VALUBusy 98%,
// VGPR 60-64, no spill). Deviations that regressed: ext_vector state (r4: 163us,
// r7: 117us), 1024-thread multi-batch blocks (r8: 991us scratch-spill),
// pass-1 peeling / code duplication (r9: 84us, I-fetch stalls). Do not restructure.
template<int BIT>
__device__ __forceinline__ void g_u2(float* V, const float* u) {
    const float u00r = u[0], u00i = u[1], u01r = u[2], u01i = u[3];
    #pragma unroll
    for (int p = 0; p < 16; ++p) {
        if (p & BIT) continue;
        const int q = p | BIT;
        float a0r = V[p], a0i = V[16 + p], a1r = V[q], a1i = V[16 + q];
        V[p]      =  u00r * a0r - u00i * a0i + u01r * a1r - u01i * a1i;
        V[16 + p] =  u00r * a0i + u00i * a0r + u01r * a1i + u01i * a1r;
        V[q]      = -u01r * a0r - u01i * a0i + u00r * a1r + u00i * a1i;
        V[16 + q] = -u01r * a0i + u01i * a0r + u00r * a1i - u00i * a1r;
    }
}

template<int CBIT, int TBIT>
__device__ __forceinline__ void g_crx_pre(float* V, float s, float c) {
    #pragma unroll
    for (int p = 0; p < 16; ++p) {
        if (!(p & CBIT) || (p & TBIT)) continue;   // control=1, target=0 rows
        const int q = p | TBIT;
        float a0r = V[p], a0i = V[16 + p], a1r = V[q], a1i = V[16 + q];
        V[p]      = c * a0r + s * a1i;
        V[16 + p] = c * a0i - s * a1r;
        V[q]      = c * a1r + s * a0i;
        V[16 + q] = c * a1i - s * a0r;
    }
}

__device__ __forceinline__ void apply_layer_pre(float* V, const float (&u)[4][4],
                                                const float (&cs)[8][2]) {
    g_u2<8>(V, u[0]); g_u2<4>(V, u[1]); g_u2<2>(V, u[2]); g_u2<1>(V, u[3]);
    g_crx_pre<8, 4>(V, cs[0][0], cs[0][1]);
    g_crx_pre<4, 2>(V, cs[1][0], cs[1][1]);
    g_crx_pre<2, 1>(V, cs[2][0], cs[2][1]);
    g_crx_pre<1, 8>(V, cs[3][0], cs[3][1]);
    g_crx_pre<1, 2>(V, cs[4][0], cs[4][1]);
    g_crx_pre<2, 4>(V, cs[5][0], cs[5][1]);
    g_crx_pre<4, 8>(V, cs[6][0], cs[6][1]);
    g_crx_pre<8, 1>(V, cs[7][0], cs[7][1]);
}

// Reduce-scatter halving step; template-constant indices (round-3-verified).
template<int S, int HALF>
__device__ __forceinline__ void rstep(float* V, int lane) {
    const bool hi = (lane >> S) & 1;
    #pragma unroll
    for (int j = 0; j < HALF; ++j) {
        float send = hi ? V[j] : V[j + HALF];
        float keep = hi ? V[j + HALF] : V[j];
        V[j] = keep + __shfl_xor(send, 1 << S, 64);
    }
}

// One block per batch element. Thread t simulates timestep t (t>=200: coeff 0).
extern "C" __global__ void __launch_bounds__(BLK)
qac_kernel(const float* __restrict__ tp,    // (B, T, NROTS)
           const float* __restrict__ poly,  // (DEG+1,)
           const float* __restrict__ mixr,  // (T,)
           const float* __restrict__ mixi,  // (T,)
           const float* __restrict__ qff,   // (20,)
           float* __restrict__ out)         // (B, 12)
{
    __shared__ float s_red[4][32];   // per-wave reduced values (value-indexed)
    __shared__ float s_w[32];        // work vector  (0..15 re, 16..31 im)
    __shared__ float s_acc[32];      // QSVT accumulator, same layout

    const int b    = blockIdx.x;
    const int tid  = threadIdx.x;
    const int lane = tid & 63;
    const int wv   = tid >> 6;

    if (tid < 32) {
        s_w[tid]   = (tid == 0) ? 1.f : 0.f;
        s_acc[tid] = (tid == 0) ? poly[0] : 0.f;
    }

    float cr_ = 0.f, ci_ = 0.f;
    if (tid < TSTEPS) { cr_ = mixr[tid]; ci_ = mixi[tid]; }
    const int mt = (tid < TSTEPS) ? tid : (TSTEPS - 1);
    const float4* p4 = (const float4*)(tp + (size_t)b * (TSTEPS * NROTS) + mt * NROTS);

    // ---- hoist ALL trig out of the QSVT loop (params identical each pass) ----
    float tu[2][4][4];   // [layer][wire][u00r,u00i,u01r,u01i]
    float tc[2][8][2];   // [layer][crx gate][s,c]
    #pragma unroll
    for (int L = 0; L < 2; ++L) {
        float4 f0 = p4[5*L+0], f1 = p4[5*L+1], f2v = p4[5*L+2], f3 = p4[5*L+3], f4 = p4[5*L+4];
        make_u(0.5f*f0.x,  0.5f*f0.y,  0.5f*f0.z,  tu[L][0]);
        make_u(0.5f*f0.w,  0.5f*f1.x,  0.5f*f1.y,  tu[L][1]);
        make_u(0.5f*f1.z,  0.5f*f1.w,  0.5f*f2v.x, tu[L][2]);
        make_u(0.5f*f2v.y, 0.5f*f2v.z, 0.5f*f2v.w, tu[L][3]);
        fsc(0.5f*f3.x, tc[L][0][0], tc[L][0][1]);
        fsc(0.5f*f3.y, tc[L][1][0], tc[L][1][1]);
        fsc(0.5f*f3.z, tc[L][2][0], tc[L][2][1]);
        fsc(0.5f*f3.w, tc[L][3][0], tc[L][3][1]);
        fsc(0.5f*f4.x, tc[L][4][0], tc[L][4][1]);
        fsc(0.5f*f4.y, tc[L][5][0], tc[L][5][1]);
        fsc(0.5f*f4.z, tc[L][6][0], tc[L][6][1]);
        fsc(0.5f*f4.w, tc[L][7][0], tc[L][7][1]);
    }

    // reduce-scatter destination: value index bitrev5(lane&31) (verified round 2)
    const int vidx = ((lane & 1) << 4) | ((lane & 2) << 2) | (lane & 4) |
                     ((lane & 8) >> 2) | ((lane & 16) >> 4);

    __syncthreads();

    #pragma unroll 1
    for (int k = 1; k <= DEG; ++k) {
        float V[32];
        #pragma unroll
        for (int i = 0; i < 32; ++i) V[i] = s_w[i];

        apply_layer_pre(V, tu[0], tc[0]);
        apply_layer_pre(V, tu[1], tc[1]);

        // scale by this timestep's LCU coefficient (0 for lanes t>=200)
        #pragma unroll
        for (int i = 0; i < 16; ++i) {
            float r = V[i], im = V[16 + i];
            V[i]      = r * cr_ - im * ci_;
            V[16 + i] = r * ci_ + im * cr_;
        }

        // reduce-scatter over lane bits 0..4, then full add over bit 5
        rstep<0, 16>(V, lane);
        rstep<1, 8>(V, lane);
        rstep<2, 4>(V, lane);
        rstep<3, 2>(V, lane);
        rstep<4, 1>(V, lane);
        float tot = V[0] + __shfl_xor(V[0], 32, 64);
        if (lane < 32) s_red[wv][vidx] = tot;

        __syncthreads();
        if (tid < 32) {
            float r = s_red[0][tid] + s_red[1][tid] + s_red[2][tid] + s_red[3][tid];
            s_w[tid] = r;
            s_acc[tid] += poly[k] * r;
        }
        __syncthreads();
    }

    // ---- finalize on wave 0, lane-per-amplitude (verified round 2) ----
    if (tid < 16) {
        const int l = tid;
        float l1 = fabsf(poly[0]) + fabsf(poly[1]) + fabsf(poly[2]) + fabsf(poly[3]);
        float inv = 1.f / l1;
        float ar = s_acc[l] * inv, ai = s_acc[16 + l] * inv;
        float n2 = ar * ar + ai * ai;
        #pragma unroll
        for (int o = 1; o < 16; o <<= 1) n2 += __shfl_xor(n2, o, 64);
        float sc = 1.f / (sqrtf(n2) + 1e-9f);
        ar *= sc; ai *= sc;

        float s, c, pr, pi, se, ce, t0;
        #pragma unroll
        for (int w = 0; w < 4; ++w) {
            const int BIT = 8 >> w;
            fsc(0.5f * qff[3 * w + 0], s, c);            // RX
            pr = __shfl_xor(ar, BIT, 64); pi = __shfl_xor(ai, BIT, 64);
            t0 = c * ar + s * pi; ai = c * ai - s * pr; ar = t0;
            fsc(0.5f * qff[3 * w + 1], s, c);            // RY
            pr = __shfl_xor(ar, BIT, 64); pi = __shfl_xor(ai, BIT, 64);
            se = (l & BIT) ? s : -s;
            t0 = c * ar + se * pr; ai = c * ai + se * pi; ar = t0;
            fsc(0.5f * qff[3 * w + 2], s, c);            // RZ
            se = (l & BIT) ? s : -s;
            t0 = c * ar - se * ai; ai = c * ai + se * ar; ar = t0;
        }
        #define CRXF(CB, TB, hp) { fsc(0.5f * (hp), s, c);                        \
            pr = __shfl_xor(ar, TB, 64); pi = __shfl_xor(ai, TB, 64);             \
            ce = (l & CB) ? c : 1.f; se = (l & CB) ? s : 0.f;                     \
            t0 = ce * ar + se * pi; ai = ce * ai - se * pr; ar = t0; }
        CRXF(8, 4, qff[12]) CRXF(4, 2, qff[13]) CRXF(2, 1, qff[14]) CRXF(1, 8, qff[15])
        CRXF(1, 2, qff[16]) CRXF(2, 4, qff[17]) CRXF(4, 8, qff[18]) CRXF(8, 1, qff[19])
        #undef CRXF

        float* o = out + (size_t)b * 12;
        #pragma unroll
        for (int w = 0; w < 4; ++w) {
            const int BIT = 8 >> w;
            pr = __shfl_xor(ar, BIT, 64); pi = __shfl_xor(ai, BIT, 64);
            float m = (l & BIT) ? 0.f : 1.f;
            float X = m * 2.f * (ar * pr + ai * pi);
            float Y = m * 2.f * (ar * pi - ai * pr);
            float Z = m * (ar * ar + ai * ai - pr * pr - pi * pi);
            #pragma unroll
            for (int of = 1; of < 16; of <<= 1) {
                X += __shfl_xor(X, of, 64);
                Y += __shfl_xor(Y, of, 64);
                Z += __shfl_xor(Z, of, 64);
            }
            if (l == 0) { o[w] = X; o[4 + w] = Y; o[8 + w] = Z; }
        }
    }
}

extern "C" void kernel_launch(void* const* d_in, const int* in_sizes, int n_in,
                              void* d_out, int out_size, void* d_ws, size_t ws_size,
                              hipStream_t stream) {
    const float* tp   = (const float*)d_in[0];
    const float* poly = (const float*)d_in[1];
    const float* mixr = (const float*)d_in[2];
    const float* mixi = (const float*)d_in[3];
    const float* qff  = (const float*)d_in[4];
    float* out = (float*)d_out;
    const int B = in_sizes[0] / (TSTEPS * NROTS);   // 2048
    qac_kernel<<<dim3(B), dim3(BLK), 0, stream>>>(tp, poly, mixr, mixi, qff, out);
}